// Round 10
// baseline (47.878 us; speedup 1.0000x reference)
//
#include <hip/hip_runtime.h>
#include <hip/hip_bf16.h>
#include <math.h>

#define T 4000
#define C 128
#define NB 800                 // T/5
#define NSTRIPE 25             // T/160 stripes of 160 i-rows
#define KSPLIT 25              // k-slices; NT=10 k-tiles per block
#define NT 10
#define CFRAC (1598.0f/3995.0f)

typedef short bf16x8 __attribute__((ext_vector_type(8)));
typedef float f32x4 __attribute__((ext_vector_type(4)));

// float -> bf16 bits, round-to-nearest-even
__device__ inline unsigned short f2bf(float f) {
    union { float f; unsigned u; } v; v.f = f;
    unsigned r = v.u + 0x7fffu + ((v.u >> 16) & 1u);
    return (unsigned short)(r >> 16);
}

__device__ inline bf16x8 pack8(const float4& u, const float4& v) {
    bf16x8 o;
    o[0] = (short)f2bf(u.x); o[1] = (short)f2bf(u.y);
    o[2] = (short)f2bf(u.z); o[3] = (short)f2bf(u.w);
    o[4] = (short)f2bf(v.x); o[5] = (short)f2bf(v.y);
    o[6] = (short)f2bf(v.z); o[7] = (short)f2bf(v.w);
    return o;
}

__device__ inline float sq8(const float4& u, const float4& v) {
    return u.x*u.x + u.y*u.y + u.z*u.z + u.w*u.w
         + v.x*v.x + v.y*v.y + v.z*v.z + v.w*v.w;
}

// ---------------- Kernel 1: fused norm + partial rowsums ----------------
// grid (NSTRIPE, KSPLIT) x 640 threads (10 waves x 16 i-rows = 160 rows/block).
// MFMA computes RAW bf16 dot products; cosine normalization applied post-MFMA:
// s = acc[j] * inv_i[j] * inv_k  (~15 VALU/tile/lane, vs r5's ~200 per-element).
// A norms: fp32 sumsq once per block (lane holds full row across hi-groups,
// 2 shfl_xor folds), redistributed with 4 __shfl. B-tile norms: staging waves
// compute chunk sumsq from the fp32 they already hold -> sN[buf][w][r]; readers
// sum 4 partials + rsqrt. Staging: fp32 loads, convert to bf16, write-late,
// 2 tiles per barrier (4 buffers). No xnb buffer, no norm kernel.
__global__ __launch_bounds__(640) void rowsum_kernel(const float* __restrict__ x,
                                                     float* __restrict__ rpart,
                                                     float* __restrict__ out) {
    __shared__ __hip_bfloat16 sB[4][2048];   // 4 x 4KB bf16 tile buffers
    __shared__ float sN[4][4][16];           // [buf][kc-chunk][row] sumsq partials

    const int bi = blockIdx.x;      // stripe 0..24
    const int ks = blockIdx.y;      // k-slice 0..24
    const int tid = threadIdx.x;
    if (bi == 0 && ks == 0 && tid == 0) out[0] = 0.f;  // visible to K2 after boundary
    const int w = tid >> 6, lane = tid & 63;
    const int r = lane & 15, hi = lane >> 4;
    const int ko = hi * 8;
    const int i0 = bi * 160 + w * 16;
    const int kt0 = ks * NT;

    // ---- A rows: raw fp32 -> bf16 frags + fp32 inv-norms ----
    const float* arow = x + (size_t)(i0 + r) * C;
    float ss = 0.f;
    bf16x8 afrag[4];
#pragma unroll
    for (int kc = 0; kc < 4; ++kc) {
        float4 u = *(const float4*)(arow + kc * 32 + ko);
        float4 v = *(const float4*)(arow + kc * 32 + ko + 4);
        ss += sq8(u, v);
        afrag[kc] = pack8(u, v);
    }
    ss += __shfl_xor(ss, 16);
    ss += __shfl_xor(ss, 32);
    const float invr = 1.0f / fmaxf(sqrtf(ss), 1e-8f);   // inv-norm of row i0+r
    float invi[4];
#pragma unroll
    for (int j = 0; j < 4; ++j) invi[j] = __shfl(invr, hi * 4 + j);  // rows hi*4+j

    // staging source base (valid for w<4): row kt*16+r, channels w*32+ko
    const float* bsrc = x + (size_t)r * C + w * 32 + ko;

    // ---- prologue: stage tiles 0,1 ----
    if (w < 4) {
#pragma unroll
        for (int tt = 0; tt < 2; ++tt) {
            const float* p = bsrc + (size_t)(kt0 + tt) * 16 * C;
            float4 u = *(const float4*)p;
            float4 v = *(const float4*)(p + 4);
            float ps = sq8(u, v);
            ps += __shfl_xor(ps, 16);
            ps += __shfl_xor(ps, 32);                     // chunk-w sumsq of row r
            *(bf16x8*)&sB[tt][w * 512 + lane * 8] = pack8(u, v);
            if (hi == 0) sN[tt][w][r] = ps;
        }
    }
    __syncthreads();

    f32x4 rsum = {0.f, 0.f, 0.f, 0.f};
    for (int tp = 0; tp < NT / 2; ++tp) {
        float4 u0, v0, u1, v1;
        const bool doStage = (w < 4) && (tp + 1 < NT / 2);
        if (doStage) {   // issue early: loads in flight across the compute phase
            const float* p0 = bsrc + (size_t)(kt0 + 2 * tp + 2) * 16 * C;
            const float* p1 = bsrc + (size_t)(kt0 + 2 * tp + 3) * 16 * C;
            u0 = *(const float4*)p0; v0 = *(const float4*)(p0 + 4);
            u1 = *(const float4*)p1; v1 = *(const float4*)(p1 + 4);
        }

        // compute tiles 2tp, 2tp+1
#pragma unroll
        for (int tt = 0; tt < 2; ++tt) {
            const int b = (2 * tp + tt) & 3;
            float n2 = sN[b][0][r] + sN[b][1][r] + sN[b][2][r] + sN[b][3][r];
            float invk = 1.0f / fmaxf(sqrtf(n2), 1e-8f);  // inv-norm of col row
            f32x4 acc = {0.f, 0.f, 0.f, 0.f};
#pragma unroll
            for (int kc = 0; kc < 4; ++kc) {
                bf16x8 bf = *(bf16x8*)&sB[b][kc * 512 + lane * 8];
                acc = __builtin_amdgcn_mfma_f32_16x16x32_bf16(afrag[kc], bf, acc, 0, 0, 0);
            }
#pragma unroll
            for (int j = 0; j < 4; ++j)
                rsum[j] += __expf(acc[j] * (invi[j] * invk));
        }

        if (doStage) {   // write late; target buffers not in use this period
            float ps0 = sq8(u0, v0);
            ps0 += __shfl_xor(ps0, 16);
            ps0 += __shfl_xor(ps0, 32);
            float ps1 = sq8(u1, v1);
            ps1 += __shfl_xor(ps1, 16);
            ps1 += __shfl_xor(ps1, 32);
            const int b0 = (2 * tp + 2) & 3, b1 = (2 * tp + 3) & 3;
            *(bf16x8*)&sB[b0][w * 512 + lane * 8] = pack8(u0, v0);
            *(bf16x8*)&sB[b1][w * 512 + lane * 8] = pack8(u1, v1);
            if (hi == 0) { sN[b0][w][r] = ps0; sN[b1][w][r] = ps1; }
        }
        __syncthreads();
    }

    // fold the 16 k-columns (lane bits 0..3), keep hi groups separate
#pragma unroll
    for (int off = 1; off < 16; off <<= 1)
#pragma unroll
        for (int j = 0; j < 4; ++j) rsum[j] += __shfl_xor(rsum[j], off);

    if (r == 0)
        *(f32x4*)(rpart + (size_t)ks * T + i0 + hi * 4) = rsum;
}

// ---------------- Kernel 2: per-5-block loss (one block per 5-block) ----------------
__global__ __launch_bounds__(64) void loss_kernel(const float* __restrict__ x,
                                                  const float* __restrict__ rpart,
                                                  const int* __restrict__ kuai2p,
                                                  float* __restrict__ out) {
    __shared__ float xs[5][C];
    __shared__ float d[5][5];
    __shared__ float rsp[5][5];
    const int b = blockIdx.x;
    const int base = b * 5;
    const int t = threadIdx.x;

    // cooperative rowsum gather: thread t<25 sums 5 partials for row t/5
    if (t < 25) {
        int pr = t / 5, chunk = t % 5;
        float s = 0.f;
#pragma unroll
        for (int k2 = 0; k2 < 5; ++k2)
            s += rpart[(size_t)(chunk * 5 + k2) * T + base + pr];
        rsp[pr][chunk] = s;
    }

    // load 5 raw fp32 rows (160 float4)
    for (int i = t; i < 160; i += 64) {
        int row = i >> 5, c4 = i & 31;
        *(float4*)&xs[row][c4 * 4] = *(const float4*)(x + (size_t)(base + row) * C + c4 * 4);
    }
    __syncthreads();

    if (t < 25) {
        int pi = t / 5, pj = t % 5;
        float s = 0.f;
#pragma unroll
        for (int c = 0; c < C; ++c) s += xs[pi][c] * xs[pj][c];
        d[pi][pj] = s;
    }
    __syncthreads();

    float contrib = 0.f;
    if (t < 20) {
        int pi = t >> 2, rr = t & 3;
        int pj = rr + (rr >= pi ? 1 : 0);
        float sii = d[pi][pi];
        float bsum = 0.f, sij = 0.f;
#pragma unroll
        for (int m = 0; m < 5; ++m) {
            float s = d[pi][m] * rsqrtf(sii * d[m][m]);   // cosine sim, fp32
            bsum += __expf(s);
            if (m == pj) sij = s;
        }
        float rs = rsp[pi][0] + rsp[pi][1] + rsp[pi][2] + rsp[pi][3] + rsp[pi][4];
        float negE = CFRAC * (rs - bsum);                 // E[neg_sum]
        contrib = sij - __logf(negE + __expf(sij));       // log(pos/(neg+pos))
    }
#pragma unroll
    for (int off = 32; off; off >>= 1) contrib += __shfl_xor(contrib, off);

    if (t == 0) {
        int k = *kuai2p;
        atomicAdd(out, contrib * (-1.0f / ((float)NB * (float)k * (float)(k - 1))));
    }
}

extern "C" void kernel_launch(void* const* d_in, const int* in_sizes, int n_in,
                              void* d_out, int out_size, void* d_ws, size_t ws_size,
                              hipStream_t stream) {
    const float* x = (const float*)d_in[0];
    const int* kuai2 = (const int*)d_in[1];
    float* out = (float*)d_out;

    float* rpart = (float*)d_ws;             // KSPLIT*T floats = 400 KB

    dim3 g1(NSTRIPE, KSPLIT);
    rowsum_kernel<<<g1, 640, 0, stream>>>(x, rpart, out);

    loss_kernel<<<NB, 64, 0, stream>>>(x, rpart, kuai2, out);
}

// Round 11
// 35.200 us; speedup vs baseline: 1.3602x; 1.3602x over previous
//
#include <hip/hip_runtime.h>
#include <hip/hip_bf16.h>
#include <math.h>

#define T 4000
#define C 128
#define NB 800                 // T/5
#define NSTRIPE 25             // T/160 stripes of 160 i-rows
#define KSPLIT 25              // k-slices; NT=10 k-tiles per block
#define NT 10
#define NBLK (NSTRIPE*KSPLIT)  // 625
#define CFRAC (1598.0f/3995.0f)

typedef short bf16x8 __attribute__((ext_vector_type(8)));
typedef float f32x4 __attribute__((ext_vector_type(4)));

// float -> bf16 bits, round-to-nearest-even (inputs are normal finite floats)
__device__ inline unsigned short f2bf(float f) {
    union { float f; unsigned u; } v; v.f = f;
    unsigned r = v.u + 0x7fffu + ((v.u >> 16) & 1u);
    return (unsigned short)(r >> 16);
}

// ---------------- Kernel 0: normalize rows -> bf16 xnb; zero out ----------------
// 250 blocks x 1024 threads (16 rows/block).
__global__ __launch_bounds__(1024) void norm_kernel(const float* __restrict__ x,
                                                    __hip_bfloat16* __restrict__ xnb,
                                                    float* __restrict__ out) {
    if (blockIdx.x == 0 && threadIdx.x == 0) out[0] = 0.f;  // visible to K2 after boundary
    const int row = blockIdx.x * 16 + (threadIdx.x >> 6);
    const int lane = threadIdx.x & 63;
    const float* xr = x + (size_t)row * C;
    float2 v = *(const float2*)(xr + lane * 2);
    float ss = v.x * v.x + v.y * v.y;
    for (int off = 32; off; off >>= 1) ss += __shfl_xor(ss, off);
    float inv = 1.0f / fmaxf(sqrtf(ss), 1e-8f);
    unsigned o = (unsigned)f2bf(v.x * inv) | ((unsigned)f2bf(v.y * inv) << 16);
    *(unsigned*)((unsigned short*)xnb + (size_t)row * C + lane * 2) = o;
}

// ---------------- Kernel 1: partial rowsums; LDS-staged B, XCD-clustered ----------------
// 625 blocks x 640 threads (10 waves x 16 i-rows = 160 rows/stripe).
// XCD clustering: blocks land on XCD bid%8 (round-robin). We remap so each XCD
// gets a CONTIGUOUS range of cell index c (ks-major) => ~3-4 consecutive k-slices
// x all 25 stripes per XCD: B-slices are fetched from L3 once per XCD then
// L2-hit; A-stripes get ~3x L2 reuse. Cuts L3-sourced traffic ~3-5x (the r9
// bottleneck: ~50MB at ~2.8TB/s effective cross-XCD rate ~= 18us).
// Schedule per block: 4 LDS tile buffers, 2 tiles per barrier period, staging
// waves (w<4) issue-early/write-late. Frag layout: lane (r=lane&15, hi=lane>>4)
// holds row ..+r, ch kc*32+hi*8..+8. C/D frag: col k = lane&15, row i = hi*4+j.
__global__ __launch_bounds__(640) void rowsum_kernel(const __hip_bfloat16* __restrict__ xnb,
                                                     float* __restrict__ rpart) {
    __shared__ __hip_bfloat16 sB[4][2048];   // 4 x 4KB tile buffers

    // ---- XCD-cluster remap: bijective bid -> (bi, ks) ----
    const int bid = blockIdx.x;              // 0..624
    const int xcd = bid & 7;
    const int k8  = bid >> 3;                // 0..78 (xcd 0), 0..77 (others)
    const int c   = (xcd == 0 ? 0 : 79 + 78 * (xcd - 1)) + k8;   // 0..624, contiguous per XCD
    const int bi  = c % NSTRIPE;             // stripe 0..24
    const int ks  = c / NSTRIPE;             // k-slice 0..24 (contiguous range per XCD)

    const int tid = threadIdx.x;
    const int w = tid >> 6, lane = tid & 63;
    const int r = lane & 15, hi = lane >> 4;
    const int ko = hi * 8;
    const int i0 = bi * 160 + w * 16;
    const int kt0 = ks * NT;

    // A frags (held in regs for the whole sweep)
    bf16x8 afrag[4];
    const __hip_bfloat16* arow = xnb + (size_t)(i0 + r) * C;
#pragma unroll
    for (int kc = 0; kc < 4; ++kc)
        afrag[kc] = *(const bf16x8*)(arow + kc * 32 + ko);

    // staging lane's per-tile source base (valid for w<4): row kt*16+r, ch w*32+ko
    const __hip_bfloat16* bsrc = xnb + (size_t)r * C + w * 32 + ko;

    // prologue: stage tiles 0,1
    if (w < 4) {
        bf16x8 s0 = *(const bf16x8*)(bsrc + (size_t)(kt0 + 0) * 16 * C);
        bf16x8 s1 = *(const bf16x8*)(bsrc + (size_t)(kt0 + 1) * 16 * C);
        *(bf16x8*)&sB[0][w * 512 + lane * 8] = s0;
        *(bf16x8*)&sB[1][w * 512 + lane * 8] = s1;
    }
    __syncthreads();

    f32x4 rsum = {0.f, 0.f, 0.f, 0.f};
    for (int tp = 0; tp < NT / 2; ++tp) {
        bf16x8 stg0, stg1;
        const bool doStage = (w < 4) && (tp + 1 < NT / 2);
        if (doStage) {   // issue early: 2 tiles in flight across the whole compute phase
            stg0 = *(const bf16x8*)(bsrc + (size_t)(kt0 + 2 * tp + 2) * 16 * C);
            stg1 = *(const bf16x8*)(bsrc + (size_t)(kt0 + 2 * tp + 3) * 16 * C);
        }

        f32x4 acc0 = {0.f, 0.f, 0.f, 0.f}, acc1 = {0.f, 0.f, 0.f, 0.f};
#pragma unroll
        for (int kc = 0; kc < 4; ++kc) {
            bf16x8 b0 = *(bf16x8*)&sB[(2 * tp) & 3][kc * 512 + lane * 8];
            acc0 = __builtin_amdgcn_mfma_f32_16x16x32_bf16(afrag[kc], b0, acc0, 0, 0, 0);
        }
#pragma unroll
        for (int kc = 0; kc < 4; ++kc) {
            bf16x8 b1 = *(bf16x8*)&sB[(2 * tp + 1) & 3][kc * 512 + lane * 8];
            acc1 = __builtin_amdgcn_mfma_f32_16x16x32_bf16(afrag[kc], b1, acc1, 0, 0, 0);
        }
#pragma unroll
        for (int j = 0; j < 4; ++j) rsum[j] += __expf(acc0[j]) + __expf(acc1[j]);

        if (doStage) {   // write late; target buffers not in use this period
            *(bf16x8*)&sB[(2 * tp + 2) & 3][w * 512 + lane * 8] = stg0;
            *(bf16x8*)&sB[(2 * tp + 3) & 3][w * 512 + lane * 8] = stg1;
        }
        __syncthreads();
    }

    // fold the 16 k-columns (lane bits 0..3), keep hi groups separate
#pragma unroll
    for (int off = 1; off < 16; off <<= 1)
#pragma unroll
        for (int j = 0; j < 4; ++j) rsum[j] += __shfl_xor(rsum[j], off);

    if (r == 0)
        *(f32x4*)(rpart + (size_t)ks * T + i0 + hi * 4) = rsum;
}

// ---------------- Kernel 2: per-5-block loss (one block per 5-block) ----------------
__global__ __launch_bounds__(64) void loss_kernel(const float* __restrict__ x,
                                                  const float* __restrict__ rpart,
                                                  const int* __restrict__ kuai2p,
                                                  float* __restrict__ out) {
    __shared__ float xs[5][C];
    __shared__ float d[5][5];
    __shared__ float rsp[5][5];
    const int b = blockIdx.x;
    const int base = b * 5;
    const int t = threadIdx.x;

    // cooperative rowsum gather: thread t<25 sums 5 partials for row t/5
    if (t < 25) {
        int pr = t / 5, chunk = t % 5;
        float s = 0.f;
#pragma unroll
        for (int k2 = 0; k2 < 5; ++k2)
            s += rpart[(size_t)(chunk * 5 + k2) * T + base + pr];
        rsp[pr][chunk] = s;
    }

    // load 5 raw fp32 rows (160 float4)
    for (int i = t; i < 160; i += 64) {
        int row = i >> 5, c4 = i & 31;
        *(float4*)&xs[row][c4 * 4] = *(const float4*)(x + (size_t)(base + row) * C + c4 * 4);
    }
    __syncthreads();

    if (t < 25) {
        int pi = t / 5, pj = t % 5;
        float s = 0.f;
#pragma unroll
        for (int c = 0; c < C; ++c) s += xs[pi][c] * xs[pj][c];
        d[pi][pj] = s;
    }
    __syncthreads();

    float contrib = 0.f;
    if (t < 20) {
        int pi = t >> 2, rr = t & 3;
        int pj = rr + (rr >= pi ? 1 : 0);
        float sii = d[pi][pi];
        float bsum = 0.f, sij = 0.f;
#pragma unroll
        for (int m = 0; m < 5; ++m) {
            float s = d[pi][m] * rsqrtf(sii * d[m][m]);   // cosine sim, fp32
            bsum += __expf(s);
            if (m == pj) sij = s;
        }
        float rs = rsp[pi][0] + rsp[pi][1] + rsp[pi][2] + rsp[pi][3] + rsp[pi][4];
        float negE = CFRAC * (rs - bsum);                 // E[neg_sum]
        contrib = sij - __logf(negE + __expf(sij));       // log(pos/(neg+pos))
    }
#pragma unroll
    for (int off = 32; off; off >>= 1) contrib += __shfl_xor(contrib, off);

    if (t == 0) {
        int k = *kuai2p;
        atomicAdd(out, contrib * (-1.0f / ((float)NB * (float)k * (float)(k - 1))));
    }
}

extern "C" void kernel_launch(void* const* d_in, const int* in_sizes, int n_in,
                              void* d_out, int out_size, void* d_ws, size_t ws_size,
                              hipStream_t stream) {
    const float* x = (const float*)d_in[0];
    const int* kuai2 = (const int*)d_in[1];
    float* out = (float*)d_out;

    float* rpart = (float*)d_ws;                             // KSPLIT*T floats = 400 KB
    __hip_bfloat16* xnb = (__hip_bfloat16*)(rpart + KSPLIT * T);

    norm_kernel<<<T / 16, 1024, 0, stream>>>(x, xnb, out);

    rowsum_kernel<<<NBLK, 640, 0, stream>>>(xnb, rpart);

    loss_kernel<<<NB, 64, 0, stream>>>(x, rpart, kuai2, out);
}